// Round 2
// baseline (101.433 us; speedup 1.0000x reference)
//
#include <hip/hip_runtime.h>

// Split pipeline: k0 W-transpose -> k1 QKV GEMM (no LDS/barriers) -> k2 attention.
// fp16 MFMA 16x16x32: A row=lane&15,k=8*(lane>>4)+i; B col=lane&15,k=8*(lane>>4)+i;
//                     C/D col=lane&15, row=4*(lane>>4)+reg.

#define B_ 256
#define T_ 256
#define C_ 384
#define H_ 64

typedef __attribute__((ext_vector_type(4))) float     f32x4;
typedef __attribute__((ext_vector_type(8))) _Float16  f16x8;
typedef __attribute__((ext_vector_type(4))) _Float16  f16x4;

#define MFMA16(a, b, c) __builtin_amdgcn_mfma_f32_16x16x32_f16((a), (b), (c), 0, 0, 0)

// ---------------- workspace layout (bytes) ----------------
constexpr size_t WT_OFF = 0;                       // [192][384] f16 (q|k|v rows)
constexpr size_t QH_OFF = 147456;                  // [65536][64] f16, pre-scaled
constexpr size_t KH_OFF = QH_OFF + 8388608;        // [65536][64] f16
constexpr size_t VT_OFF = KH_OFF + 8388608;        // [256][64][256] f16 (V^T per batch)
constexpr size_t WS_NEED = VT_OFF + 8388608;       // 25,313,280 B

// ================= k0: W -> Wt (cast+transpose) =================
__global__ void w_transpose(const float* __restrict__ Wq,
                            const float* __restrict__ Wk,
                            const float* __restrict__ Wv,
                            _Float16* __restrict__ Wt) {
    int e = blockIdx.x * 256 + threadIdx.x;      // 0..73727
    int h = e & 63;
    int k = (e >> 6) % 384;
    int p = e / 24576;
    const float* W = (p == 0) ? Wq : (p == 1) ? Wk : Wv;
    Wt[(size_t)(p * 64 + h) * 384 + k] = (_Float16)W[k * 64 + h];
}

// ================= k1: QKV = x @ [Wq|Wk|Wv] =================
// 512 blocks (128 rows each) x 384 threads (6 waves = 2M x 3N), wave tile 64x64.
__global__ __launch_bounds__(384, 3) void qkv_gemm(
    const float* __restrict__ x, const _Float16* __restrict__ Wt,
    _Float16* __restrict__ Qh, _Float16* __restrict__ Kh,
    _Float16* __restrict__ Vt)
{
    const int tid = threadIdx.x, lane = tid & 63, wid = tid >> 6;
    const int lo = lane & 15, hi = lane >> 4;
    const int wr = wid / 3, wc = wid % 3;
    const int blk = blockIdx.x;
    const int row0 = blk * 128 + wr * 64;
    const float* xw = x + (size_t)row0 * C_;

    f32x4 acc[4][4] = {};
    for (int kk = 0; kk < C_; kk += 32) {
        f16x8 af[4];
        #pragma unroll
        for (int rt = 0; rt < 4; ++rt) {
            const float* xp = xw + (size_t)(16 * rt + lo) * C_ + kk + 8 * hi;
            float4 u = *(const float4*)xp;
            float4 v = *(const float4*)(xp + 4);
            af[rt] = (f16x8){(_Float16)u.x, (_Float16)u.y, (_Float16)u.z, (_Float16)u.w,
                             (_Float16)v.x, (_Float16)v.y, (_Float16)v.z, (_Float16)v.w};
        }
        #pragma unroll
        for (int nt = 0; nt < 4; ++nt) {
            f16x8 bf = *(const f16x8*)(Wt + (size_t)(wc * 64 + 16 * nt + lo) * C_ + kk + 8 * hi);
            #pragma unroll
            for (int rt = 0; rt < 4; ++rt)
                acc[rt][nt] = MFMA16(af[rt], bf, acc[rt][nt]);
        }
    }

    // epilogue: n = wc*64+16*nt+lo; class uniform per (wc,nt)
    const int b   = blk >> 1;
    const int tl0 = (blk & 1) * 128 + wr * 64;
    #pragma unroll
    for (int nt = 0; nt < 4; ++nt) {
        const int nbase = wc * 64 + 16 * nt;
        const int ncls  = nbase >> 6;            // 0=Q 1=K 2=V (uniform)
        const int n     = nbase + lo;
        #pragma unroll
        for (int rt = 0; rt < 4; ++rt) {
            const int t = row0 + 16 * rt + 4 * hi;   // global row for reg 0
            if (ncls == 0) {
                #pragma unroll
                for (int reg = 0; reg < 4; ++reg)
                    Qh[(size_t)(t + reg) * 64 + n] = (_Float16)(0.125f * acc[rt][nt][reg]);
            } else if (ncls == 1) {
                #pragma unroll
                for (int reg = 0; reg < 4; ++reg)
                    Kh[(size_t)(t + reg) * 64 + (n - 64)] = (_Float16)acc[rt][nt][reg];
            } else {
                f16x4 pv = {(_Float16)acc[rt][nt][0], (_Float16)acc[rt][nt][1],
                            (_Float16)acc[rt][nt][2], (_Float16)acc[rt][nt][3]};
                *(f16x4*)(Vt + (size_t)b * 16384 + (size_t)(n - 128) * 256
                          + tl0 + 16 * rt + 4 * hi) = pv;
            }
        }
    }
}

// ================= k2: attention per batch =================
// 256 blocks x 512 threads (8 indep waves, 32 q-rows each). LDS only for P-bounce.
constexpr int SP = 72;

__global__ __launch_bounds__(512, 2) void attn(
    const _Float16* __restrict__ Qh, const _Float16* __restrict__ Kh,
    const _Float16* __restrict__ Vt, float* __restrict__ out)
{
    __shared__ _Float16 Ps[8 * 32 * SP];
    const int tid = threadIdx.x, lane = tid & 63, wid = tid >> 6;
    const int lo = lane & 15, hi = lane >> 4;
    const int b = blockIdx.x;
    const int ctmax = 2 * wid + 1;               // last S column-tile with valid entries

    // Q fragments (own 32 rows)
    f16x8 aq[2][2];
    #pragma unroll
    for (int rt = 0; rt < 2; ++rt)
        #pragma unroll
        for (int ks = 0; ks < 2; ++ks)
            aq[rt][ks] = *(const f16x8*)(Qh + (size_t)(b * 256 + 32 * wid + 16 * rt + lo) * 64
                                         + 32 * ks + 8 * hi);

    // S = Q K^T (skip fully-masked column tiles)
    f32x4 sacc[2][16] = {};
    #pragma unroll
    for (int ct = 0; ct < 16; ++ct) {
        if (ct <= ctmax) {
            #pragma unroll
            for (int ks = 0; ks < 2; ++ks) {
                f16x8 bk = *(const f16x8*)(Kh + (size_t)(b * 256 + 16 * ct + lo) * 64
                                           + 32 * ks + 8 * hi);
                sacc[0][ct] = MFMA16(aq[0][ks], bk, sacc[0][ct]);
                sacc[1][ct] = MFMA16(aq[1][ks], bk, sacc[1][ct]);
            }
        }
    }

    // causal mask + softmax (row across 16-lane group)
    #pragma unroll
    for (int rt = 0; rt < 2; ++rt) {
        #pragma unroll
        for (int reg = 0; reg < 4; ++reg) {
            const int rowg = 32 * wid + 16 * rt + 4 * hi + reg;
            float m = -1e30f;
            #pragma unroll
            for (int ct = 0; ct < 16; ++ct) if (ct <= ctmax) {
                float v = sacc[rt][ct][reg];
                v = (16 * ct + lo <= rowg) ? v : -1e30f;
                sacc[rt][ct][reg] = v;
                m = fmaxf(m, v);
            }
            #pragma unroll
            for (int s = 1; s < 16; s <<= 1) m = fmaxf(m, __shfl_xor(m, s, 16));
            float l = 0.f;
            #pragma unroll
            for (int ct = 0; ct < 16; ++ct) if (ct <= ctmax) {
                float v = sacc[rt][ct][reg];
                float p = (v > -1e29f) ? __expf(v - m) : 0.f;
                sacc[rt][ct][reg] = p;
                l += p;
            }
            #pragma unroll
            for (int s = 1; s < 16; s <<= 1) l += __shfl_xor(l, s, 16);
            float rinv = 1.f / l;
            #pragma unroll
            for (int ct = 0; ct < 16; ++ct) if (ct <= ctmax) sacc[rt][ct][reg] *= rinv;
        }
    }

    // O = P V (bounce P through per-wave LDS chunk; V^T fragments straight from L2)
    f32x4 oacc[2][4] = {};
    _Float16* Pw = Ps + wid * 32 * SP;
    const int kcmax = ctmax >> 2;
    #pragma unroll
    for (int kc = 0; kc < 4; ++kc) {
        if (kc <= kcmax) {
            #pragma unroll
            for (int rt = 0; rt < 2; ++rt)
                #pragma unroll
                for (int c = 0; c < 4; ++c) {
                    const int ct = 4 * kc + c;
                    #pragma unroll
                    for (int reg = 0; reg < 4; ++reg) {
                        float v = (ct <= ctmax) ? sacc[rt][ct][reg] : 0.f;
                        Pw[(16 * rt + 4 * hi + reg) * SP + c * 16 + lo] = (_Float16)v;
                    }
                }
            asm volatile("s_waitcnt lgkmcnt(0)" ::: "memory");
            #pragma unroll
            for (int ks = 0; ks < 2; ++ks) {
                f16x8 a0 = *(const f16x8*)(Pw + lo * SP + 32 * ks + 8 * hi);
                f16x8 a1 = *(const f16x8*)(Pw + (16 + lo) * SP + 32 * ks + 8 * hi);
                #pragma unroll
                for (int ht = 0; ht < 4; ++ht) {
                    f16x8 bv = *(const f16x8*)(Vt + (size_t)b * 16384 + (size_t)(16 * ht + lo) * 256
                                               + 64 * kc + 32 * ks + 8 * hi);
                    oacc[0][ht] = MFMA16(a0, bv, oacc[0][ht]);
                    oacc[1][ht] = MFMA16(a1, bv, oacc[1][ht]);
                }
            }
            asm volatile("s_waitcnt lgkmcnt(0)" ::: "memory");
        }
    }

    float* ob = out + (size_t)b * (T_ * H_);
    #pragma unroll
    for (int rt = 0; rt < 2; ++rt)
        #pragma unroll
        for (int ht = 0; ht < 4; ++ht)
            #pragma unroll
            for (int reg = 0; reg < 4; ++reg) {
                const int t = 32 * wid + 16 * rt + 4 * hi + reg;
                ob[t * H_ + 16 * ht + lo] = oacc[rt][ht][reg];
            }
}

// ================= fallback (R1 fused kernel) if ws is too small =================
constexpr int FSX = 40, FSW = 40, FSQ = 72, FSV = 264, FSP = 72;
constexpr int FOFF_K = 256 * FSQ;
constexpr int FOFF_V = FOFF_K + 256 * FSQ;
constexpr int FOFF_U = FOFF_V + 64 * FSV;
constexpr int FOFF_W = FOFF_U + 256 * FSX;
constexpr int FSMEM_BYTES = (FOFF_U + 8 * 32 * FSP) * 2;

__global__ __launch_bounds__(512, 2) void head_fused(
    const float* __restrict__ x, const float* __restrict__ Wq,
    const float* __restrict__ Wk, const float* __restrict__ Wv,
    float* __restrict__ out)
{
    extern __shared__ _Float16 sm[];
    _Float16* Qs = sm;
    _Float16* Ks = sm + FOFF_K;
    _Float16* Vt = sm + FOFF_V;
    _Float16* Xs = sm + FOFF_U;
    _Float16* Wt = sm + FOFF_W;
    _Float16* Ps = sm + FOFF_U;

    const int tid = threadIdx.x, lane = tid & 63, wid = tid >> 6;
    const int lo = lane & 15, hi = lane >> 4;
    const int b = blockIdx.x;
    const float* xb = x + (size_t)b * (T_ * C_);

    f32x4 acc[3][2][4] = {};
    for (int kk = 0; kk < C_; kk += 32) {
        #pragma unroll
        for (int i = 0; i < 4; ++i) {
            int idx = tid + i * 512, r = idx >> 3, c4 = (idx & 7) * 4;
            float4 xv = *(const float4*)(xb + r * C_ + kk + c4);
            f16x4 hv = {(_Float16)xv.x, (_Float16)xv.y, (_Float16)xv.z, (_Float16)xv.w};
            *(f16x4*)(Xs + r * FSX + c4) = hv;
        }
        #pragma unroll
        for (int i = 0; i < 4; ++i) {
            int idx = tid + i * 512, kc = idx >> 6, h = idx & 63;
            Wt[(0 * 64 + h) * FSW + kc] = (_Float16)Wq[(kk + kc) * H_ + h];
            Wt[(1 * 64 + h) * FSW + kc] = (_Float16)Wk[(kk + kc) * H_ + h];
            Wt[(2 * 64 + h) * FSW + kc] = (_Float16)Wv[(kk + kc) * H_ + h];
        }
        __syncthreads();
        f16x8 a0 = *(const f16x8*)(Xs + (32 * wid + lo) * FSX + 8 * hi);
        f16x8 a1 = *(const f16x8*)(Xs + (32 * wid + 16 + lo) * FSX + 8 * hi);
        #pragma unroll
        for (int p = 0; p < 3; ++p)
            #pragma unroll
            for (int nt = 0; nt < 4; ++nt) {
                f16x8 bf = *(const f16x8*)(Wt + (p * 64 + nt * 16 + lo) * FSW + 8 * hi);
                acc[p][0][nt] = MFMA16(a0, bf, acc[p][0][nt]);
                acc[p][1][nt] = MFMA16(a1, bf, acc[p][1][nt]);
            }
        __syncthreads();
    }
    #pragma unroll
    for (int rt = 0; rt < 2; ++rt)
        #pragma unroll
        for (int nt = 0; nt < 4; ++nt)
            #pragma unroll
            for (int reg = 0; reg < 4; ++reg) {
                int srow = 32 * wid + 16 * rt + 4 * hi + reg, h = 16 * nt + lo;
                Qs[srow * FSQ + h] = (_Float16)(0.125f * acc[0][rt][nt][reg]);
                Ks[srow * FSQ + h] = (_Float16)acc[1][rt][nt][reg];
                Vt[h * FSV + srow] = (_Float16)acc[2][rt][nt][reg];
            }
    __syncthreads();

    f32x4 sacc[2][16] = {};
    #pragma unroll
    for (int ks = 0; ks < 2; ++ks) {
        f16x8 a0 = *(const f16x8*)(Qs + (32 * wid + lo) * FSQ + 32 * ks + 8 * hi);
        f16x8 a1 = *(const f16x8*)(Qs + (32 * wid + 16 + lo) * FSQ + 32 * ks + 8 * hi);
        #pragma unroll
        for (int ct = 0; ct < 16; ++ct) {
            f16x8 bf = *(const f16x8*)(Ks + (16 * ct + lo) * FSQ + 32 * ks + 8 * hi);
            sacc[0][ct] = MFMA16(a0, bf, sacc[0][ct]);
            sacc[1][ct] = MFMA16(a1, bf, sacc[1][ct]);
        }
    }
    #pragma unroll
    for (int rt = 0; rt < 2; ++rt)
        #pragma unroll
        for (int reg = 0; reg < 4; ++reg) {
            const int rowg = 32 * wid + 16 * rt + 4 * hi + reg;
            float m = -1e30f;
            #pragma unroll
            for (int ct = 0; ct < 16; ++ct) {
                float v = sacc[rt][ct][reg];
                v = (16 * ct + lo <= rowg) ? v : -1e30f;
                sacc[rt][ct][reg] = v;
                m = fmaxf(m, v);
            }
            #pragma unroll
            for (int s = 1; s < 16; s <<= 1) m = fmaxf(m, __shfl_xor(m, s, 16));
            float l = 0.f;
            #pragma unroll
            for (int ct = 0; ct < 16; ++ct) {
                float v = sacc[rt][ct][reg];
                float p = (v > -1e29f) ? __expf(v - m) : 0.f;
                sacc[rt][ct][reg] = p;
                l += p;
            }
            #pragma unroll
            for (int s = 1; s < 16; s <<= 1) l += __shfl_xor(l, s, 16);
            float rinv = 1.f / l;
            #pragma unroll
            for (int ct = 0; ct < 16; ++ct) sacc[rt][ct][reg] *= rinv;
        }
    f32x4 oacc[2][4] = {};
    _Float16* Pw = Ps + wid * 32 * FSP;
    #pragma unroll
    for (int kc = 0; kc < 4; ++kc) {
        #pragma unroll
        for (int rt = 0; rt < 2; ++rt)
            #pragma unroll
            for (int c = 0; c < 4; ++c)
                #pragma unroll
                for (int reg = 0; reg < 4; ++reg)
                    Pw[(16 * rt + 4 * hi + reg) * FSP + c * 16 + lo] =
                        (_Float16)sacc[rt][4 * kc + c][reg];
        asm volatile("s_waitcnt lgkmcnt(0)" ::: "memory");
        #pragma unroll
        for (int ks = 0; ks < 2; ++ks) {
            f16x8 a0 = *(const f16x8*)(Pw + lo * FSP + 32 * ks + 8 * hi);
            f16x8 a1 = *(const f16x8*)(Pw + (16 + lo) * FSP + 32 * ks + 8 * hi);
            #pragma unroll
            for (int ht = 0; ht < 4; ++ht) {
                f16x8 bv = *(const f16x8*)(Vt + (16 * ht + lo) * FSV + 64 * kc + 32 * ks + 8 * hi);
                oacc[0][ht] = MFMA16(a0, bv, oacc[0][ht]);
                oacc[1][ht] = MFMA16(a1, bv, oacc[1][ht]);
            }
        }
        asm volatile("s_waitcnt lgkmcnt(0)" ::: "memory");
    }
    float* ob = out + (size_t)b * (T_ * H_);
    #pragma unroll
    for (int rt = 0; rt < 2; ++rt)
        #pragma unroll
        for (int ht = 0; ht < 4; ++ht)
            #pragma unroll
            for (int reg = 0; reg < 4; ++reg) {
                int t = 32 * wid + 16 * rt + 4 * hi + reg;
                ob[t * H_ + 16 * ht + lo] = oacc[rt][ht][reg];
            }
}

extern "C" void kernel_launch(void* const* d_in, const int* in_sizes, int n_in,
                              void* d_out, int out_size, void* d_ws, size_t ws_size,
                              hipStream_t stream) {
    const float* x  = (const float*)d_in[0];
    const float* Wq = (const float*)d_in[1];
    const float* Wk = (const float*)d_in[2];
    const float* Wv = (const float*)d_in[3];
    float* out = (float*)d_out;
    (void)in_sizes; (void)n_in; (void)out_size;

    if (ws_size < WS_NEED) {
        hipFuncSetAttribute(reinterpret_cast<const void*>(head_fused),
                            hipFuncAttributeMaxDynamicSharedMemorySize, FSMEM_BYTES);
        head_fused<<<dim3(B_), dim3(512), FSMEM_BYTES, stream>>>(x, Wq, Wk, Wv, out);
        return;
    }

    char* ws = (char*)d_ws;
    _Float16* Wt = (_Float16*)(ws + WT_OFF);
    _Float16* Qh = (_Float16*)(ws + QH_OFF);
    _Float16* Kh = (_Float16*)(ws + KH_OFF);
    _Float16* Vt = (_Float16*)(ws + VT_OFF);

    w_transpose<<<dim3(288), dim3(256), 0, stream>>>(Wq, Wk, Wv, Wt);
    qkv_gemm<<<dim3(512), dim3(384), 0, stream>>>(x, Wt, Qh, Kh, Vt);
    attn<<<dim3(B_), dim3(512), 0, stream>>>(Qh, Kh, Vt, out);
}